// Round 1
// baseline (194.233 us; speedup 1.0000x reference)
//
#include <hip/hip_runtime.h>
#include <math.h>

#define DEV __device__ __forceinline__

// Soft gate: c0 + ca*a + cb*b + cab*(a*b)
DEV float gev(float4 c, float a, float b) {
    return fmaf(c.w, a * b, fmaf(c.z, b, fmaf(c.y, a, c.x)));
}

DEV float sel4(const float h[4], int i) {
    float r = h[0];
    r = (i == 1) ? h[1] : r;
    r = (i == 2) ? h[2] : r;
    r = (i == 3) ? h[3] : r;
    return r;
}

DEV float sel2(const float h[2], int i) { return (i == 1) ? h[1] : h[0]; }

// ---------------------------------------------------------------------------
// Kernel 1: per-gate coefficient precompute.
// Gate segments (cumulative): c1L0 64, c1L1 32, c1L2 16, c2L0 192, c2L1 96,
// c2L2 48, c3L0 576, c3L1 288, c3L2 144, fc1 20480, fc2 10240, fc3 5120.
// Total = 37296 gates. Each w row is 16 floats; emit float4{c0,ca,cb,cab}.
// ---------------------------------------------------------------------------
__global__ void coef_kernel(
    const float* __restrict__ w0, const float* __restrict__ w1,
    const float* __restrict__ w2, const float* __restrict__ w3,
    const float* __restrict__ w4, const float* __restrict__ w5,
    const float* __restrict__ w6, const float* __restrict__ w7,
    const float* __restrict__ w8, const float* __restrict__ w9,
    const float* __restrict__ w10, const float* __restrict__ w11,
    float4* __restrict__ out)
{
    int t = blockIdx.x * blockDim.x + threadIdx.x;
    if (t >= 37296) return;
    const float* wrow;
    if      (t < 64)    wrow = w0  + t * 16;
    else if (t < 96)    wrow = w1  + (t - 64) * 16;
    else if (t < 112)   wrow = w2  + (t - 96) * 16;
    else if (t < 304)   wrow = w3  + (t - 112) * 16;
    else if (t < 400)   wrow = w4  + (t - 304) * 16;
    else if (t < 448)   wrow = w5  + (t - 400) * 16;
    else if (t < 1024)  wrow = w6  + (t - 448) * 16;
    else if (t < 1312)  wrow = w7  + (t - 1024) * 16;
    else if (t < 1456)  wrow = w8  + (t - 1312) * 16;
    else if (t < 21936) wrow = w9  + (t - 1456) * 16;
    else if (t < 32176) wrow = w10 + (t - 21936) * 16;
    else                wrow = w11 + (t - 32176) * 16;

    float p[16];
    float mx = wrow[0];
    #pragma unroll
    for (int k = 1; k < 16; k++) mx = fmaxf(mx, wrow[k]);
    float s = 0.f;
    #pragma unroll
    for (int k = 0; k < 16; k++) { p[k] = expf(wrow[k] - mx); s += p[k]; }
    float inv = 1.f / s;
    #pragma unroll
    for (int k = 0; k < 16; k++) p[k] *= inv;

    float c0  = p[8]+p[9]+p[10]+p[11]+p[12]+p[13]+p[14]+p[15];
    float ca  = p[2]+p[3]+p[6]+p[7]-p[8]-p[9]-p[12]-p[13];
    float cb  = p[4]+p[5]+p[6]+p[7]-p[8]-p[9]-p[10]-p[11];
    float cab = p[1]-p[2]-p[4]-2.f*p[6]-p[7]+p[8]+2.f*p[9]+p[11]+p[13]-p[14];
    out[t] = make_float4(c0, ca, cb, cab);
}

// ---------------------------------------------------------------------------
// Fused conv(logic-tree) + orpool. One thread per pooled output element.
// in:  [B, CIN, HIN, HIN]   out: [B, F, HP, HP], HP = (HIN+2P-KS+1)/2
// Patch index t in [0, CIN*KS*KS): c = t/(KS*KS), ki = (t%(KS*KS))/KS, kj = %KS
// ---------------------------------------------------------------------------
template <int CIN, int KS, int PAD, int HIN, int F, int BINARIZE>
__global__ void conv_kernel(
    const float* __restrict__ in,
    const int* __restrict__ idx0,   // [2, F, 4]
    const int* __restrict__ idx1,   // [2, F, 2]
    const int* __restrict__ idx2,   // [2, F, 1]
    const float4* __restrict__ cf0,
    const float4* __restrict__ cf1,
    const float4* __restrict__ cf2,
    float* __restrict__ out)
{
    constexpr int HCONV = HIN + 2 * PAD - KS + 1;
    constexpr int HP = HCONV / 2;
    constexpr int TOTAL = 100 * F * HP * HP;
    int t = blockIdx.x * blockDim.x + threadIdx.x;
    if (t >= TOTAL) return;
    int pw = t % HP;
    int ph = (t / HP) % HP;
    int f  = (t / (HP * HP)) % F;
    int b  = t / (F * HP * HP);

    int a0[4], b0[4];
    #pragma unroll
    for (int g = 0; g < 4; g++) { a0[g] = idx0[f*4+g]; b0[g] = idx0[F*4 + f*4+g]; }
    int a1[2], b1[2];
    #pragma unroll
    for (int g = 0; g < 2; g++) { a1[g] = idx1[f*2+g]; b1[g] = idx1[F*2 + f*2+g]; }
    int a2 = idx2[f], b2 = idx2[F + f];
    float4 C0[4] = {cf0[f*4], cf0[f*4+1], cf0[f*4+2], cf0[f*4+3]};
    float4 C1[2] = {cf1[f*2], cf1[f*2+1]};
    float4 C2 = cf2[f];

    const float* inb = in + (long)b * CIN * HIN * HIN;
    float m = -1e30f;
    #pragma unroll
    for (int dy = 0; dy < 2; dy++) {
        #pragma unroll
        for (int dx = 0; dx < 2; dx++) {
            int oh = 2 * ph + dy, ow = 2 * pw + dx;
            float h0[4];
            #pragma unroll
            for (int g = 0; g < 4; g++) {
                float va, vb;
                {
                    int tt = a0[g];
                    int c = tt / (KS * KS), r = tt % (KS * KS);
                    int y = oh + r / KS - PAD, x = ow + r % KS - PAD;
                    bool ok = (PAD == 0) || (y >= 0 && y < HIN && x >= 0 && x < HIN);
                    float v = ok ? inb[(c * HIN + y) * HIN + x] : 0.f;
                    va = BINARIZE ? (v > 0.5f ? 1.f : 0.f) : v;
                }
                {
                    int tt = b0[g];
                    int c = tt / (KS * KS), r = tt % (KS * KS);
                    int y = oh + r / KS - PAD, x = ow + r % KS - PAD;
                    bool ok = (PAD == 0) || (y >= 0 && y < HIN && x >= 0 && x < HIN);
                    float v = ok ? inb[(c * HIN + y) * HIN + x] : 0.f;
                    vb = BINARIZE ? (v > 0.5f ? 1.f : 0.f) : v;
                }
                h0[g] = gev(C0[g], va, vb);
            }
            float h1[2];
            #pragma unroll
            for (int g = 0; g < 2; g++)
                h1[g] = gev(C1[g], sel4(h0, a1[g]), sel4(h0, b1[g]));
            float v = gev(C2, sel2(h1, a2), sel2(h1, b2));
            m = fmaxf(m, v);
        }
    }
    out[t] = m;
}

// ---------------------------------------------------------------------------
// FC logic layer: out[b,o] = gate(h[b,i0[o]], h[b,i1[o]])
// ---------------------------------------------------------------------------
__global__ void fc_kernel(const float* __restrict__ h, int Din,
                          const int* __restrict__ idx, int Dout,
                          const float4* __restrict__ cf,
                          float* __restrict__ out, int total)
{
    int t = blockIdx.x * blockDim.x + threadIdx.x;
    if (t >= total) return;
    int o = t % Dout;
    int b = t / Dout;
    const float* hb = h + (long)b * Din;
    float a = hb[idx[o]];
    float bb = hb[idx[Dout + o]];
    out[t] = gev(cf[o], a, bb);
}

// ---------------------------------------------------------------------------
// GroupSum: out[b,g] = sum_{s<512} h[b, g*512+s] / 30.  One wave per output.
// ---------------------------------------------------------------------------
__global__ void gsum_kernel(const float* __restrict__ h, float* __restrict__ out)
{
    int og = blockIdx.x;           // [0, 1000)
    int b = og / 10, g = og % 10;
    const float* p = h + (long)b * 5120 + g * 512;
    float s = 0.f;
    for (int i = threadIdx.x; i < 512; i += 64) s += p[i];
    #pragma unroll
    for (int off = 32; off > 0; off >>= 1) s += __shfl_down(s, off, 64);
    if (threadIdx.x == 0) out[og] = s * (1.f / 30.f);
}

extern "C" void kernel_launch(void* const* d_in, const int* in_sizes, int n_in,
                              void* d_out, int out_size, void* d_ws, size_t ws_size,
                              hipStream_t stream)
{
    const float* x     = (const float*)d_in[0];
    const int*   c1i0  = (const int*)d_in[1];  const float* c1w0 = (const float*)d_in[2];
    const int*   c1i1  = (const int*)d_in[3];  const float* c1w1 = (const float*)d_in[4];
    const int*   c1i2  = (const int*)d_in[5];  const float* c1w2 = (const float*)d_in[6];
    const int*   c2i0  = (const int*)d_in[7];  const float* c2w0 = (const float*)d_in[8];
    const int*   c2i1  = (const int*)d_in[9];  const float* c2w1 = (const float*)d_in[10];
    const int*   c2i2  = (const int*)d_in[11]; const float* c2w2 = (const float*)d_in[12];
    const int*   c3i0  = (const int*)d_in[13]; const float* c3w0 = (const float*)d_in[14];
    const int*   c3i1  = (const int*)d_in[15]; const float* c3w1 = (const float*)d_in[16];
    const int*   c3i2  = (const int*)d_in[17]; const float* c3w2 = (const float*)d_in[18];
    const int*   fc1i  = (const int*)d_in[19]; const float* fc1w = (const float*)d_in[20];
    const int*   fc2i  = (const int*)d_in[21]; const float* fc2w = (const float*)d_in[22];
    const int*   fc3i  = (const int*)d_in[23]; const float* fc3w = (const float*)d_in[24];

    char* ws = (char*)d_ws;
    float4* coef = (float4*)ws;                 // 37296 float4 = 596,736 B
    float* p1 = (float*)(ws + 596736);          // [100,16,12,12]  = 230400
    float* p2 = p1 + 230400;                    // [100,48,6,6]    = 172800
    float* p3 = p2 + 172800;                    // [100,144,3,3]   = 129600
    float* f1 = p3 + 129600;                    // [100,20480]
    float* f2 = f1 + 2048000;                   // [100,10240]
    float* f3 = f2 + 1024000;                   // [100,5120]

    coef_kernel<<<(37296 + 255) / 256, 256, 0, stream>>>(
        c1w0, c1w1, c1w2, c2w0, c2w1, c2w2, c3w0, c3w1, c3w2,
        fc1w, fc2w, fc3w, coef);

    // c1: [100,1,28,28] -> conv5 pad0 -> [100,16,24,24] -> pool -> [100,16,12,12]
    conv_kernel<1, 5, 0, 28, 16, 1><<<900, 256, 0, stream>>>(
        x, c1i0, c1i1, c1i2, coef + 0, coef + 64, coef + 96, p1);

    // c2: [100,16,12,12] -> conv3 pad1 -> [100,48,12,12] -> pool -> [100,48,6,6]
    conv_kernel<16, 3, 1, 12, 48, 0><<<675, 256, 0, stream>>>(
        p1, c2i0, c2i1, c2i2, coef + 112, coef + 304, coef + 400, p2);

    // c3: [100,48,6,6] -> conv3 pad1 -> [100,144,6,6] -> pool -> [100,144,3,3]
    conv_kernel<48, 3, 1, 6, 144, 0><<<(129600 + 255) / 256, 256, 0, stream>>>(
        p2, c3i0, c3i1, c3i2, coef + 448, coef + 1024, coef + 1312, p3);

    fc_kernel<<<8000, 256, 0, stream>>>(p3, 1296, fc1i, 20480, coef + 1456, f1, 2048000);
    fc_kernel<<<4000, 256, 0, stream>>>(f1, 20480, fc2i, 10240, coef + 21936, f2, 1024000);
    fc_kernel<<<2000, 256, 0, stream>>>(f2, 10240, fc3i, 5120, coef + 32176, f3, 512000);

    gsum_kernel<<<1000, 64, 0, stream>>>(f3, (float*)d_out);
}

// Round 2
// 157.367 us; speedup vs baseline: 1.2343x; 1.2343x over previous
//
#include <hip/hip_runtime.h>
#include <hip/hip_fp16.h>
#include <math.h>

#define DEV __device__ __forceinline__

// Soft gate: c0 + ca*a + cb*b + cab*(a*b)
DEV float gev(float4 c, float a, float b) {
    return fmaf(c.w, a * b, fmaf(c.z, b, fmaf(c.y, a, c.x)));
}

DEV float sel4(const float h[4], int i) {
    float r = h[0];
    r = (i == 1) ? h[1] : r;
    r = (i == 2) ? h[2] : r;
    r = (i == 3) ? h[3] : r;
    return r;
}

DEV float sel2(const float h[2], int i) { return (i == 1) ? h[1] : h[0]; }

// ---------------------------------------------------------------------------
// Kernel 1: per-gate coefficient precompute (softmax over 16 ops -> affine
// basis {1, a, b, ab}).  Segments (cumulative float4 offsets):
// c1L0 0(64) c1L1 64(32) c1L2 96(16) c2L0 112(192) c2L1 304(96) c2L2 400(48)
// c3L0 448(576) c3L1 1024(288) c3L2 1312(144) fc1 1456(20480)
// fc2 21936(10240) fc3 32176(5120).  Total 37296.
// ---------------------------------------------------------------------------
__global__ void coef_kernel(
    const float* __restrict__ w0, const float* __restrict__ w1,
    const float* __restrict__ w2, const float* __restrict__ w3,
    const float* __restrict__ w4, const float* __restrict__ w5,
    const float* __restrict__ w6, const float* __restrict__ w7,
    const float* __restrict__ w8, const float* __restrict__ w9,
    const float* __restrict__ w10, const float* __restrict__ w11,
    float4* __restrict__ out)
{
    int t = blockIdx.x * blockDim.x + threadIdx.x;
    if (t >= 37296) return;
    const float* wrow;
    if      (t < 64)    wrow = w0  + t * 16;
    else if (t < 96)    wrow = w1  + (t - 64) * 16;
    else if (t < 112)   wrow = w2  + (t - 96) * 16;
    else if (t < 304)   wrow = w3  + (t - 112) * 16;
    else if (t < 400)   wrow = w4  + (t - 304) * 16;
    else if (t < 448)   wrow = w5  + (t - 400) * 16;
    else if (t < 1024)  wrow = w6  + (t - 448) * 16;
    else if (t < 1312)  wrow = w7  + (t - 1024) * 16;
    else if (t < 1456)  wrow = w8  + (t - 1312) * 16;
    else if (t < 21936) wrow = w9  + (t - 1456) * 16;
    else if (t < 32176) wrow = w10 + (t - 21936) * 16;
    else                wrow = w11 + (t - 32176) * 16;

    float p[16];
    float mx = wrow[0];
    #pragma unroll
    for (int k = 1; k < 16; k++) mx = fmaxf(mx, wrow[k]);
    float s = 0.f;
    #pragma unroll
    for (int k = 0; k < 16; k++) { p[k] = __expf(wrow[k] - mx); s += p[k]; }
    float inv = 1.f / s;
    #pragma unroll
    for (int k = 0; k < 16; k++) p[k] *= inv;

    float c0  = p[8]+p[9]+p[10]+p[11]+p[12]+p[13]+p[14]+p[15];
    float ca  = p[2]+p[3]+p[6]+p[7]-p[8]-p[9]-p[12]-p[13];
    float cb  = p[4]+p[5]+p[6]+p[7]-p[8]-p[9]-p[10]-p[11];
    float cab = p[1]-p[2]-p[4]-2.f*p[6]-p[7]+p[8]+2.f*p[9]+p[11]+p[13]-p[14];
    out[t] = make_float4(c0, ca, cb, cab);
}

// ---------------------------------------------------------------------------
// Conv stage (device): logic-tree conv + orpool, input/output in LDS.
// Sin: [CIN][HIN][HIN] floats, Sout: [F][HP][HP] floats.
// ---------------------------------------------------------------------------
template <int CIN, int KS, int PAD, int HIN, int F>
DEV void conv_stage(const float* Sin, float* Sout,
                    const int* __restrict__ idx0, const int* __restrict__ idx1,
                    const int* __restrict__ idx2,
                    const float4* __restrict__ cf0, const float4* __restrict__ cf1,
                    const float4* __restrict__ cf2, int tid, int nthr)
{
    constexpr int HP = (HIN + 2 * PAD - KS + 1) / 2;
    for (int t = tid; t < F * HP * HP; t += nthr) {
        int pw = t % HP;
        int ph = (t / HP) % HP;
        int f  = t / (HP * HP);

        int a0[4], b0[4];
        #pragma unroll
        for (int g = 0; g < 4; g++) { a0[g] = idx0[f*4+g]; b0[g] = idx0[F*4 + f*4+g]; }
        int a1[2], b1[2];
        #pragma unroll
        for (int g = 0; g < 2; g++) { a1[g] = idx1[f*2+g]; b1[g] = idx1[F*2 + f*2+g]; }
        int a2 = idx2[f], b2 = idx2[F + f];
        float4 C0[4] = {cf0[f*4], cf0[f*4+1], cf0[f*4+2], cf0[f*4+3]};
        float4 C1[2] = {cf1[f*2], cf1[f*2+1]};
        float4 C2 = cf2[f];

        float m = -1e30f;
        #pragma unroll
        for (int dy = 0; dy < 2; dy++) {
            #pragma unroll
            for (int dx = 0; dx < 2; dx++) {
                int oh = 2 * ph + dy, ow = 2 * pw + dx;
                float h0[4];
                #pragma unroll
                for (int g = 0; g < 4; g++) {
                    float va, vb;
                    {
                        int tt = a0[g];
                        int c = tt / (KS * KS), r = tt % (KS * KS);
                        int y = oh + r / KS - PAD, x = ow + r % KS - PAD;
                        bool ok = (PAD == 0) || (y >= 0 && y < HIN && x >= 0 && x < HIN);
                        va = ok ? Sin[(c * HIN + y) * HIN + x] : 0.f;
                    }
                    {
                        int tt = b0[g];
                        int c = tt / (KS * KS), r = tt % (KS * KS);
                        int y = oh + r / KS - PAD, x = ow + r % KS - PAD;
                        bool ok = (PAD == 0) || (y >= 0 && y < HIN && x >= 0 && x < HIN);
                        vb = ok ? Sin[(c * HIN + y) * HIN + x] : 0.f;
                    }
                    h0[g] = gev(C0[g], va, vb);
                }
                float h1[2];
                #pragma unroll
                for (int g = 0; g < 2; g++)
                    h1[g] = gev(C1[g], sel4(h0, a1[g]), sel4(h0, b1[g]));
                float v = gev(C2, sel2(h1, a2), sel2(h1, b2));
                m = fmaxf(m, v);
            }
        }
        Sout[t] = m;
    }
}

// ---------------------------------------------------------------------------
// FC logic-layer stage (device): Sout[o] = gate(Sin[i0[o]], Sin[i1[o]])
// ---------------------------------------------------------------------------
template <int DOUT, typename TIN, typename TOUT>
DEV void fc_stage(const TIN* Sin, TOUT* Sout, const int* __restrict__ idx,
                  const float4* __restrict__ cf, int tid, int nthr)
{
    for (int o = tid; o < DOUT; o += nthr) {
        int ia = idx[o], ib = idx[DOUT + o];
        float4 c = cf[o];
        float a = (float)Sin[ia];
        float b = (float)Sin[ib];
        Sout[o] = (TOUT)gev(c, a, b);
    }
}

// ---------------------------------------------------------------------------
// Fused whole-network kernel: one workgroup per batch element, all
// intermediates in LDS.  Aliased static LDS layout (bytes):
//   XB [0,3136) | P1 [3136,12352) | P2 [12352,19264) | P3 [19264,24448)
//   F1 fp16 [24448,65408) | F2 fp16 [0,20480) | F3 fp32 [24448,44928)
// peak concurrent = fc2: F1+F2 = 61440 B; allocation = 65408 B < 64 KiB.
// ---------------------------------------------------------------------------
__global__ __launch_bounds__(512, 1) void fused_kernel(
    const float* __restrict__ x,
    const int* __restrict__ c1i0, const int* __restrict__ c1i1, const int* __restrict__ c1i2,
    const int* __restrict__ c2i0, const int* __restrict__ c2i1, const int* __restrict__ c2i2,
    const int* __restrict__ c3i0, const int* __restrict__ c3i1, const int* __restrict__ c3i2,
    const int* __restrict__ fc1i, const int* __restrict__ fc2i, const int* __restrict__ fc3i,
    const float4* __restrict__ coef,
    float* __restrict__ out)
{
    __shared__ __align__(16) char S[65408];
    float*  XB = (float*)S;                 // 784
    float*  P1 = (float*)S + 784;           // 2304 (16x12x12)
    float*  P2 = (float*)S + 3088;          // 1728 (48x6x6)
    float*  P3 = (float*)S + 4816;          // 1296 (144x3x3)
    __half* F1 = (__half*)(S + 24448);      // 20480
    __half* F2 = (__half*)(S + 0);          // 10240
    float*  F3 = (float*)(S + 24448);       // 5120

    const int b = blockIdx.x, tid = threadIdx.x;
    const float* xb = x + b * 784;
    for (int i = tid; i < 784; i += 512) XB[i] = xb[i] > 0.5f ? 1.f : 0.f;
    __syncthreads();

    conv_stage<1, 5, 0, 28, 16>(XB, P1, c1i0, c1i1, c1i2,
                                coef + 0, coef + 64, coef + 96, tid, 512);
    __syncthreads();
    conv_stage<16, 3, 1, 12, 48>(P1, P2, c2i0, c2i1, c2i2,
                                 coef + 112, coef + 304, coef + 400, tid, 512);
    __syncthreads();
    conv_stage<48, 3, 1, 6, 144>(P2, P3, c3i0, c3i1, c3i2,
                                 coef + 448, coef + 1024, coef + 1312, tid, 512);
    __syncthreads();

    fc_stage<20480>(P3, F1, fc1i, coef + 1456, tid, 512);
    __syncthreads();
    fc_stage<10240>(F1, F2, fc2i, coef + 21936, tid, 512);
    __syncthreads();
    fc_stage<5120>(F2, F3, fc3i, coef + 32176, tid, 512);
    __syncthreads();

    // GroupSum: 10 groups of 512, /30.  8 waves; wave w handles g = w, w+8.
    int wave = tid >> 6, lane = tid & 63;
    for (int g = wave; g < 10; g += 8) {
        float s = 0.f;
        #pragma unroll
        for (int i = 0; i < 8; i++) s += F3[g * 512 + i * 64 + lane];
        #pragma unroll
        for (int off = 32; off > 0; off >>= 1) s += __shfl_down(s, off, 64);
        if (lane == 0) out[b * 10 + g] = s * (1.f / 30.f);
    }
}

extern "C" void kernel_launch(void* const* d_in, const int* in_sizes, int n_in,
                              void* d_out, int out_size, void* d_ws, size_t ws_size,
                              hipStream_t stream)
{
    const float* x     = (const float*)d_in[0];
    const int*   c1i0  = (const int*)d_in[1];  const float* c1w0 = (const float*)d_in[2];
    const int*   c1i1  = (const int*)d_in[3];  const float* c1w1 = (const float*)d_in[4];
    const int*   c1i2  = (const int*)d_in[5];  const float* c1w2 = (const float*)d_in[6];
    const int*   c2i0  = (const int*)d_in[7];  const float* c2w0 = (const float*)d_in[8];
    const int*   c2i1  = (const int*)d_in[9];  const float* c2w1 = (const float*)d_in[10];
    const int*   c2i2  = (const int*)d_in[11]; const float* c2w2 = (const float*)d_in[12];
    const int*   c3i0  = (const int*)d_in[13]; const float* c3w0 = (const float*)d_in[14];
    const int*   c3i1  = (const int*)d_in[15]; const float* c3w1 = (const float*)d_in[16];
    const int*   c3i2  = (const int*)d_in[17]; const float* c3w2 = (const float*)d_in[18];
    const int*   fc1i  = (const int*)d_in[19]; const float* fc1w = (const float*)d_in[20];
    const int*   fc2i  = (const int*)d_in[21]; const float* fc2w = (const float*)d_in[22];
    const int*   fc3i  = (const int*)d_in[23]; const float* fc3w = (const float*)d_in[24];

    float4* coef = (float4*)d_ws;   // 37296 * 16 B = 596,736 B

    coef_kernel<<<(37296 + 255) / 256, 256, 0, stream>>>(
        c1w0, c1w1, c1w2, c2w0, c2w1, c2w2, c3w0, c3w1, c3w2,
        fc1w, fc2w, fc3w, coef);

    fused_kernel<<<100, 512, 0, stream>>>(
        x,
        c1i0, c1i1, c1i2, c2i0, c2i1, c2i2, c3i0, c3i1, c3i2,
        fc1i, fc2i, fc3i, coef, (float*)d_out);
}